// Round 13
// baseline (223.273 us; speedup 1.0000x reference)
//
#include <hip/hip_runtime.h>
#include <hip/hip_bf16.h>

#define SEQ 1024
#define DIM 128
#define NEG_SLOPE 0.1f

typedef __bf16 bf16x8 __attribute__((ext_vector_type(8)));
typedef float f32x4v __attribute__((ext_vector_type(4)));
typedef int   i32x4  __attribute__((ext_vector_type(4)));

__device__ __forceinline__ int fxv(int x) {
    return ((x & 3) | ((x & 1) << 2)) ^ ((x >> 2) & 7);
}
__device__ __forceinline__ int swz128(int row, int unit) {     // 128B-stride rows
    return row * 128 + ((unit ^ fxv(row >> 2)) << 4);
}
__device__ __forceinline__ int swz256(int row, int unit) {     // 256B-stride rows
    return row * 256 + ((unit ^ fxv(row >> 2)) << 4);
}
// Raw barrier: LDS-drain only — no vmcnt(0), register prefetch stays in flight
__device__ __forceinline__ void bar() {
    asm volatile("s_waitcnt lgkmcnt(0)" ::: "memory");
    __builtin_amdgcn_s_barrier();
    __builtin_amdgcn_sched_barrier(0);
}
__device__ __forceinline__ unsigned short bfb(float f) {
    __bf16 h = (__bf16)f;
    return __builtin_bit_cast(unsigned short, h);
}
__device__ __forceinline__ unsigned bpack(float a, float b) {
    return (unsigned)bfb(a) | ((unsigned)bfb(b) << 16);
}
__device__ __forceinline__ unsigned mpack(int x0, int x1) {
    unsigned m0 = (x0 != 0) ? 0x3F80u : 0u;   // bf16 1.0
    unsigned m1 = (x1 != 0) ? 0x3F80u : 0u;
    return m0 | (m1 << 16);
}

// ---------------- BK=128 kernel: 8 chunks, 9 barriers (was 16 chunks / 17) ----
// m233-style 2-phase stall: ~72% of each chunk period is stage+barrier overhead,
// invariant across 4 structural rounds. Amortize it: double the work per barrier
// phase. LDS = 2 x {mask_t[128i][128o] 32K + nodes_t[128d][128o] 32K} = 128KB
// dynamic. Everything else identical to the verified r12 kernel.
#define BK_BUF   65536
#define BK_NOFF  32768

__global__ __launch_bounds__(512, 1)
void gcn_bk128(const float* __restrict__ nodes,
               const int* __restrict__ adj,
               const float* __restrict__ W,
               const float* __restrict__ Bm,
               float* __restrict__ out)
{
    extern __shared__ unsigned char lds[];

    const int bid   = blockIdx.x;          // 256 = 32 batches x 8 itiles
    const int xcd   = bid & 7;
    const int slot  = bid >> 3;
    const int batch = ((slot >> 3) << 3) | xcd;
    const int itile = slot & 7;
    const int i0    = itile << 7;

    const int tid  = threadIdx.x;
    const int wave = tid >> 6;
    const int lane = tid & 63;
    const int wm   = wave >> 1;            // 0..3  (i 32-row slice)
    const int wn   = wave & 1;             // 0..1  (d 64-col slice)
    const int lrow = lane & 15;
    const int quad = lane >> 4;

    const int*   __restrict__ adj_b   = adj   + (size_t)batch * SEQ * SEQ;
    const float* __restrict__ nodes_b = nodes + (size_t)batch * SEQ * DIM;

    // staging: 512 threads cover 128o x 128(i|d); thread -> 8 rows x 16B
    const int o_base = (tid >> 5) * 8;     // o row group (16 groups x 8 = 128)
    const int a_col  = (tid & 31) * 4;     // i group (int4)
    const int n_col  = (tid & 31) * 4;     // d group (float4)
    const int o_unit = tid >> 5;           // 16B unit (0..15) in 256B LDS row

    f32x4v acc[2][4] = {};
    f32x4v acc_cnt[2] = {};
    bf16x8 ones;
    #pragma unroll
    for (int j = 0; j < 8; ++j) ones[j] = __builtin_bit_cast(__bf16, (unsigned short)0x3F80);

    i32x4  A0[8], A1[8];
    float4 N0[8], N1[8];

    auto load_chunk = [&](int c, i32x4 (&A)[8], float4 (&N)[8]) {
        const int* pa = adj_b + (size_t)(c * 128 + o_base) * SEQ + (i0 + a_col);
        #pragma unroll
        for (int r = 0; r < 8; ++r)
            A[r] = __builtin_nontemporal_load((const i32x4*)(pa + (size_t)r * SEQ));
        const float* pn = nodes_b + (size_t)(c * 128 + o_base) * DIM + n_col;
        #pragma unroll
        for (int r = 0; r < 8; ++r) N[r] = *(const float4*)(pn + (size_t)r * DIM);
    };

    auto write_lds = [&](int base, const i32x4 (&A)[8], const float4 (&N)[8]) {
        unsigned char* mb = lds + base;
        unsigned char* nb = lds + base + BK_NOFF;
        #pragma unroll
        for (int j = 0; j < 4; ++j) {
            uint4 u;
            u.x = mpack(A[0][j], A[1][j]);
            u.y = mpack(A[2][j], A[3][j]);
            u.z = mpack(A[4][j], A[5][j]);
            u.w = mpack(A[6][j], A[7][j]);
            *(uint4*)(mb + swz256(a_col + j, o_unit)) = u;
        }
        #pragma unroll
        for (int j = 0; j < 4; ++j) {
            uint4 u;
            u.x = bpack(((const float*)&N[0])[j], ((const float*)&N[1])[j]);
            u.y = bpack(((const float*)&N[2])[j], ((const float*)&N[3])[j]);
            u.z = bpack(((const float*)&N[4])[j], ((const float*)&N[5])[j]);
            u.w = bpack(((const float*)&N[6])[j], ((const float*)&N[7])[j]);
            *(uint4*)(nb + swz256(n_col + j, o_unit)) = u;
        }
    };

    auto compute = [&](int base) {
        const unsigned char* mb = lds + base;
        const unsigned char* nb = lds + base + BK_NOFF;
        #pragma unroll
        for (int kk = 0; kk < 4; ++kk) {
            const int un = kk * 4 + quad;  // 16B unit for o = kk*32 + quad*8
            bf16x8 av[2], bv[4];
            #pragma unroll
            for (int mf = 0; mf < 2; ++mf)
                av[mf] = *(const bf16x8*)(mb + swz256(wm * 32 + mf * 16 + lrow, un));
            #pragma unroll
            for (int nf = 0; nf < 4; ++nf)
                bv[nf] = *(const bf16x8*)(nb + swz256(wn * 64 + nf * 16 + lrow, un));
            #pragma unroll
            for (int mf = 0; mf < 2; ++mf) {
                #pragma unroll
                for (int nf = 0; nf < 4; ++nf)
                    acc[mf][nf] = __builtin_amdgcn_mfma_f32_16x16x32_bf16(av[mf], bv[nf], acc[mf][nf], 0, 0, 0);
                acc_cnt[mf] = __builtin_amdgcn_mfma_f32_16x16x32_bf16(av[mf], ones, acc_cnt[mf], 0, 0, 0);
            }
        }
    };

    // prologue: R0<-c0, R1<-c1; stage c0; R0<-c2  (2-deep in flight)
    load_chunk(0, A0, N0);
    load_chunk(1, A1, N1);
    write_lds(0, A0, N0);
    load_chunk(2, A0, N0);
    bar();

    for (int cc = 0; cc < 4; ++cc) {
        const int c0 = 2 * cc;
        compute(0);
        write_lds(BK_BUF, A1, N1);
        if (c0 + 3 < 8) load_chunk(c0 + 3, A1, N1);
        bar();
        compute(BK_BUF);
        if (c0 + 2 < 8) write_lds(0, A0, N0);
        if (c0 + 4 < 8) load_chunk(c0 + 4, A0, N0);
        bar();
    }

    // ---- epilogue (identical to r12): pooled 32K @0 + WT 32K @32K; then BT @0 ----
    #pragma unroll
    for (int mf = 0; mf < 2; ++mf) {
        #pragma unroll
        for (int r = 0; r < 4; ++r) {
            const int row = wm * 32 + mf * 16 + quad * 4 + r;
            const float cnt = acc_cnt[mf][r];
            const float inv = (cnt > 0.5f) ? 1.0f / cnt : 0.0f;
            #pragma unroll
            for (int nf = 0; nf < 4; ++nf) {
                const int col = wn * 64 + nf * 16 + lrow;
                *(unsigned short*)(lds + row * 256 + ((((col >> 3) ^ fxv(row >> 2)) << 4))
                                   + (col & 7) * 2) = bfb(acc[mf][nf][r] * inv);
            }
        }
    }

    const int n4 = (tid & 31) * 4;
    const int kg = tid >> 5;
    {
        float4 v[8];
        const float* pw = W + (size_t)(kg * 8) * DIM + n4;
        #pragma unroll
        for (int r = 0; r < 8; ++r) v[r] = *(const float4*)(pw + (size_t)r * DIM);
        #pragma unroll
        for (int j = 0; j < 4; ++j) {
            uint4 u;
            u.x = bpack(((const float*)&v[0])[j], ((const float*)&v[1])[j]);
            u.y = bpack(((const float*)&v[2])[j], ((const float*)&v[3])[j]);
            u.z = bpack(((const float*)&v[4])[j], ((const float*)&v[5])[j]);
            u.w = bpack(((const float*)&v[6])[j], ((const float*)&v[7])[j]);
            *(uint4*)(lds + 32768 + swz256(n4 + j, kg)) = u;
        }
    }
    bar();

    f32x4v acc2[2][4] = {};

    #pragma unroll
    for (int ks = 0; ks < 4; ++ks) {
        const int un = ks * 4 + quad;
        bf16x8 av[2], bv[4];
        #pragma unroll
        for (int mf = 0; mf < 2; ++mf)
            av[mf] = *(const bf16x8*)(lds + swz256(wm * 32 + mf * 16 + lrow, un));
        #pragma unroll
        for (int nf = 0; nf < 4; ++nf)
            bv[nf] = *(const bf16x8*)(lds + 32768 + swz256(wn * 64 + nf * 16 + lrow, un));
        #pragma unroll
        for (int mf = 0; mf < 2; ++mf)
            #pragma unroll
            for (int nf = 0; nf < 4; ++nf)
                acc2[mf][nf] = __builtin_amdgcn_mfma_f32_16x16x32_bf16(av[mf], bv[nf], acc2[mf][nf], 0, 0, 0);
    }
    bar();

    {
        float4 v[8];
        const float* pb = Bm + (size_t)(kg * 8) * DIM + n4;
        #pragma unroll
        for (int r = 0; r < 8; ++r) v[r] = *(const float4*)(pb + (size_t)r * DIM);
        #pragma unroll
        for (int j = 0; j < 4; ++j) {
            uint4 u;
            u.x = bpack(((const float*)&v[0])[j], ((const float*)&v[1])[j]);
            u.y = bpack(((const float*)&v[2])[j], ((const float*)&v[3])[j]);
            u.z = bpack(((const float*)&v[4])[j], ((const float*)&v[5])[j]);
            u.w = bpack(((const float*)&v[6])[j], ((const float*)&v[7])[j]);
            *(uint4*)(lds + swz256(n4 + j, kg)) = u;
        }
    }
    bar();

    #pragma unroll
    for (int ks = 0; ks < 4; ++ks) {
        const int k0 = ks * 32 + quad * 8;
        const int un = ks * 4 + quad;
        bf16x8 av[2], bv[4];
        #pragma unroll
        for (int mf = 0; mf < 2; ++mf) {
            const float* p = nodes_b + (size_t)(i0 + wm * 32 + mf * 16 + lrow) * DIM + k0;
            const float4 f1 = *(const float4*)p;
            const float4 f2 = *(const float4*)(p + 4);
            av[mf][0] = (__bf16)f1.x; av[mf][1] = (__bf16)f1.y;
            av[mf][2] = (__bf16)f1.z; av[mf][3] = (__bf16)f1.w;
            av[mf][4] = (__bf16)f2.x; av[mf][5] = (__bf16)f2.y;
            av[mf][6] = (__bf16)f2.z; av[mf][7] = (__bf16)f2.w;
        }
        #pragma unroll
        for (int nf = 0; nf < 4; ++nf)
            bv[nf] = *(const bf16x8*)(lds + swz256(wn * 64 + nf * 16 + lrow, un));
        #pragma unroll
        for (int mf = 0; mf < 2; ++mf)
            #pragma unroll
            for (int nf = 0; nf < 4; ++nf)
                acc2[mf][nf] = __builtin_amdgcn_mfma_f32_16x16x32_bf16(av[mf], bv[nf], acc2[mf][nf], 0, 0, 0);
    }

    float* out_b = out + (size_t)batch * SEQ * DIM;
    #pragma unroll
    for (int mf = 0; mf < 2; ++mf) {
        #pragma unroll
        for (int nf = 0; nf < 4; ++nf) {
            const int col = wn * 64 + nf * 16 + lrow;
            #pragma unroll
            for (int r = 0; r < 4; ++r) {
                const int row = i0 + wm * 32 + mf * 16 + quad * 4 + r;
                const float x = acc2[mf][nf][r];
                out_b[(size_t)row * DIM + col] = (x > 0.0f) ? x : NEG_SLOPE * x;
            }
        }
    }
}

// ---------------- fallback: r12 kernel verbatim (static 64KB LDS) ------------
#define BUF_STRIDE 32768
#define NODES_OFF  16384

__global__ __launch_bounds__(512, 1)
void gcn_fused_fb(const float* __restrict__ nodes,
                  const int* __restrict__ adj,
                  const float* __restrict__ W,
                  const float* __restrict__ Bm,
                  float* __restrict__ out)
{
    __shared__ alignas(16) unsigned char lds[2 * BUF_STRIDE];

    const int bid   = blockIdx.x;
    const int xcd   = bid & 7;
    const int slot  = bid >> 3;
    const int batch = ((slot >> 3) << 3) | xcd;
    const int itile = slot & 7;
    const int i0    = itile << 7;

    const int tid  = threadIdx.x;
    const int wave = tid >> 6;
    const int lane = tid & 63;
    const int wm   = wave >> 1;
    const int wn   = wave & 1;
    const int lrow = lane & 15;
    const int quad = lane >> 4;

    const int*   __restrict__ adj_b   = adj   + (size_t)batch * SEQ * SEQ;
    const float* __restrict__ nodes_b = nodes + (size_t)batch * SEQ * DIM;

    const int a_row = (tid >> 5) * 4;
    const int a_col = (tid & 31) * 4;
    const int n_col = (tid & 31) * 4;
    const int unit_s = (tid >> 5) >> 1;
    const int sub_s  = ((tid >> 5) & 1) * 8;

    f32x4v acc[2][4] = {};
    f32x4v acc_cnt[2] = {};
    bf16x8 ones;
    #pragma unroll
    for (int j = 0; j < 8; ++j) ones[j] = __builtin_bit_cast(__bf16, (unsigned short)0x3F80);

    i32x4  A0[4], A1[4];
    float4 N0[4], N1[4];

    auto load_chunk = [&](int o0, i32x4 (&A)[4], float4 (&N)[4]) {
        const int* pa = adj_b + (size_t)(o0 + a_row) * SEQ + (i0 + a_col);
        #pragma unroll
        for (int r = 0; r < 4; ++r)
            A[r] = __builtin_nontemporal_load((const i32x4*)(pa + (size_t)r * SEQ));
        const float* pn = nodes_b + (size_t)(o0 + a_row) * DIM + n_col;
        #pragma unroll
        for (int r = 0; r < 4; ++r) N[r] = *(const float4*)(pn + (size_t)r * DIM);
    };

    auto write_lds = [&](int base, const i32x4 (&A)[4], const float4 (&N)[4]) {
        unsigned char* mb = lds + base;
        unsigned char* nb = lds + base + NODES_OFF;
        #pragma unroll
        for (int j = 0; j < 4; ++j) {
            uint2 w;
            w.x = mpack(A[0][j], A[1][j]);
            w.y = mpack(A[2][j], A[3][j]);
            *(uint2*)(mb + swz128(a_col + j, unit_s) + sub_s) = w;
        }
        #pragma unroll
        for (int j = 0; j < 4; ++j) {
            uint2 w;
            w.x = bpack(((const float*)&N[0])[j], ((const float*)&N[1])[j]);
            w.y = bpack(((const float*)&N[2])[j], ((const float*)&N[3])[j]);
            *(uint2*)(nb + swz128(n_col + j, unit_s) + sub_s) = w;
        }
    };

    auto compute = [&](int base) {
        const unsigned char* mb = lds + base;
        const unsigned char* nb = lds + base + NODES_OFF;
        #pragma unroll
        for (int kk = 0; kk < 2; ++kk) {
            bf16x8 av[2], bv[4];
            #pragma unroll
            for (int mf = 0; mf < 2; ++mf)
                av[mf] = *(const bf16x8*)(mb + swz128(wm * 32 + mf * 16 + lrow, 4 * kk + quad));
            #pragma unroll
            for (int nf = 0; nf < 4; ++nf)
                bv[nf] = *(const bf16x8*)(nb + swz128(wn * 64 + nf * 16 + lrow, 4 * kk + quad));
            #pragma unroll
            for (int mf = 0; mf < 2; ++mf) {
                #pragma unroll
                for (int nf = 0; nf < 4; ++nf)
                    acc[mf][nf] = __builtin_amdgcn_mfma_f32_16x16x32_bf16(av[mf], bv[nf], acc[mf][nf], 0, 0, 0);
                acc_cnt[mf] = __builtin_amdgcn_mfma_f32_16x16x32_bf16(av[mf], ones, acc_cnt[mf], 0, 0, 0);
            }
        }
    };

    load_chunk(0,   A0, N0);
    load_chunk(64,  A1, N1);
    write_lds(0, A0, N0);
    load_chunk(128, A0, N0);
    bar();

    for (int cc = 0; cc < 8; ++cc) {
        const int c0 = cc * 2;
        compute(0);
        write_lds(BUF_STRIDE, A1, N1);
        if (c0 + 3 < 16) load_chunk((c0 + 3) * 64, A1, N1);
        bar();
        compute(BUF_STRIDE);
        if (c0 + 2 < 16) write_lds(0, A0, N0);
        if (c0 + 4 < 16) load_chunk((c0 + 4) * 64, A0, N0);
        bar();
    }

    #pragma unroll
    for (int mf = 0; mf < 2; ++mf) {
        #pragma unroll
        for (int r = 0; r < 4; ++r) {
            const int row = wm * 32 + mf * 16 + quad * 4 + r;
            const float cnt = acc_cnt[mf][r];
            const float inv = (cnt > 0.5f) ? 1.0f / cnt : 0.0f;
            #pragma unroll
            for (int nf = 0; nf < 4; ++nf) {
                const int col = wn * 64 + nf * 16 + lrow;
                *(unsigned short*)(lds + row * 256 + ((((col >> 3) ^ fxv(row >> 2)) << 4))
                                   + (col & 7) * 2) = bfb(acc[mf][nf][r] * inv);
            }
        }
    }

    const int n4 = (tid & 31) * 4;
    const int kg = tid >> 5;
    {
        float4 v[8];
        const float* pw = W + (size_t)(kg * 8) * DIM + n4;
        #pragma unroll
        for (int r = 0; r < 8; ++r) v[r] = *(const float4*)(pw + (size_t)r * DIM);
        #pragma unroll
        for (int j = 0; j < 4; ++j) {
            uint4 u;
            u.x = bpack(((const float*)&v[0])[j], ((const float*)&v[1])[j]);
            u.y = bpack(((const float*)&v[2])[j], ((const float*)&v[3])[j]);
            u.z = bpack(((const float*)&v[4])[j], ((const float*)&v[5])[j]);
            u.w = bpack(((const float*)&v[6])[j], ((const float*)&v[7])[j]);
            *(uint4*)(lds + BUF_STRIDE + swz256(n4 + j, kg)) = u;
        }
    }
    bar();

    f32x4v acc2[2][4] = {};

    #pragma unroll
    for (int ks = 0; ks < 4; ++ks) {
        const int un = ks * 4 + quad;
        bf16x8 av[2], bv[4];
        #pragma unroll
        for (int mf = 0; mf < 2; ++mf)
            av[mf] = *(const bf16x8*)(lds + swz256(wm * 32 + mf * 16 + lrow, un));
        #pragma unroll
        for (int nf = 0; nf < 4; ++nf)
            bv[nf] = *(const bf16x8*)(lds + BUF_STRIDE + swz256(wn * 64 + nf * 16 + lrow, un));
        #pragma unroll
        for (int mf = 0; mf < 2; ++mf)
            #pragma unroll
            for (int nf = 0; nf < 4; ++nf)
                acc2[mf][nf] = __builtin_amdgcn_mfma_f32_16x16x32_bf16(av[mf], bv[nf], acc2[mf][nf], 0, 0, 0);
    }
    bar();

    {
        float4 v[8];
        const float* pb = Bm + (size_t)(kg * 8) * DIM + n4;
        #pragma unroll
        for (int r = 0; r < 8; ++r) v[r] = *(const float4*)(pb + (size_t)r * DIM);
        #pragma unroll
        for (int j = 0; j < 4; ++j) {
            uint4 u;
            u.x = bpack(((const float*)&v[0])[j], ((const float*)&v[1])[j]);
            u.y = bpack(((const float*)&v[2])[j], ((const float*)&v[3])[j]);
            u.z = bpack(((const float*)&v[4])[j], ((const float*)&v[5])[j]);
            u.w = bpack(((const float*)&v[6])[j], ((const float*)&v[7])[j]);
            *(uint4*)(lds + swz256(n4 + j, kg)) = u;
        }
    }
    bar();

    #pragma unroll
    for (int ks = 0; ks < 4; ++ks) {
        const int k0 = ks * 32 + quad * 8;
        const int un = ks * 4 + quad;
        bf16x8 av[2], bv[4];
        #pragma unroll
        for (int mf = 0; mf < 2; ++mf) {
            const float* p = nodes_b + (size_t)(i0 + wm * 32 + mf * 16 + lrow) * DIM + k0;
            const float4 f1 = *(const float4*)p;
            const float4 f2 = *(const float4*)(p + 4);
            av[mf][0] = (__bf16)f1.x; av[mf][1] = (__bf16)f1.y;
            av[mf][2] = (__bf16)f1.z; av[mf][3] = (__bf16)f1.w;
            av[mf][4] = (__bf16)f2.x; av[mf][5] = (__bf16)f2.y;
            av[mf][6] = (__bf16)f2.z; av[mf][7] = (__bf16)f2.w;
        }
        #pragma unroll
        for (int nf = 0; nf < 4; ++nf)
            bv[nf] = *(const bf16x8*)(lds + swz256(wn * 64 + nf * 16 + lrow, un));
        #pragma unroll
        for (int mf = 0; mf < 2; ++mf)
            #pragma unroll
            for (int nf = 0; nf < 4; ++nf)
                acc2[mf][nf] = __builtin_amdgcn_mfma_f32_16x16x32_bf16(av[mf], bv[nf], acc2[mf][nf], 0, 0, 0);
    }

    float* out_b = out + (size_t)batch * SEQ * DIM;
    #pragma unroll
    for (int mf = 0; mf < 2; ++mf) {
        #pragma unroll
        for (int nf = 0; nf < 4; ++nf) {
            const int col = wn * 64 + nf * 16 + lrow;
            #pragma unroll
            for (int r = 0; r < 4; ++r) {
                const int row = i0 + wm * 32 + mf * 16 + quad * 4 + r;
                const float x = acc2[mf][nf][r];
                out_b[(size_t)row * DIM + col] = (x > 0.0f) ? x : NEG_SLOPE * x;
            }
        }
    }
}

extern "C" void kernel_launch(void* const* d_in, const int* in_sizes, int n_in,
                              void* d_out, int out_size, void* d_ws, size_t ws_size,
                              hipStream_t stream) {
    const float* nodes = (const float*)d_in[0];
    const int*   adj   = (const int*)d_in[1];
    const float* W     = (const float*)d_in[2];
    const float* Bm    = (const float*)d_in[3];
    float*       out   = (float*)d_out;

    // 128KB dynamic LDS opt-in (capture-safe: not a stream op). Fall back to the
    // verified 64KB BK=64 kernel if the attribute isn't honored.
    hipError_t e = hipFuncSetAttribute((const void*)gcn_bk128,
                                       hipFuncAttributeMaxDynamicSharedMemorySize,
                                       131072);
    if (e == hipSuccess) {
        gcn_bk128<<<dim3(256), dim3(512), 131072, stream>>>(nodes, adj, W, Bm, out);
    } else {
        (void)hipGetLastError();
        gcn_fused_fb<<<dim3(256), dim3(512), 0, stream>>>(nodes, adj, W, Bm, out);
    }
}

// Round 14
// 213.615 us; speedup vs baseline: 1.0452x; 1.0452x over previous
//
#include <hip/hip_runtime.h>
#include <hip/hip_bf16.h>

#define SEQ 1024
#define DIM 128
#define NEG_SLOPE 0.1f

typedef __bf16 bf16x8 __attribute__((ext_vector_type(8)));
typedef float f32x4v __attribute__((ext_vector_type(4)));
typedef int   i32x4  __attribute__((ext_vector_type(4)));

// Main-loop LDS: double-buffered {mask_t 128i x 64o bf16 (16KB) + nodes_t 128d x 64o (16KB)}
// Row stride 128 B = 8 x 16B units, XOR-swizzled (verified r2/r8/r9/r12 scheme).
#define BUF_STRIDE 32768
#define NODES_OFF  16384

__device__ __forceinline__ int fxv(int x) {
    return ((x & 3) | ((x & 1) << 2)) ^ ((x >> 2) & 7);
}
__device__ __forceinline__ int swz(int row, int unit) {        // 128B-stride rows
    return row * 128 + ((unit ^ fxv(row >> 2)) << 4);
}
__device__ __forceinline__ int swz256(int row, int unit) {     // 256B-stride rows
    return row * 256 + ((unit ^ fxv(row >> 2)) << 4);
}
// barrier with compiler memory fence (keeps ds ops inside their phase)
__device__ __forceinline__ void sbar() {
    asm volatile("s_barrier" ::: "memory");
}
// drain own LDS ops, then pin the cluster boundary (rule #18)
__device__ __forceinline__ void lgkm0() {
    asm volatile("s_waitcnt lgkmcnt(0)" ::: "memory");
    __builtin_amdgcn_sched_barrier(0);
}
// epilogue barrier (lgkm-drain + barrier), r12-verified
__device__ __forceinline__ void bar() {
    asm volatile("s_waitcnt lgkmcnt(0)" ::: "memory");
    __builtin_amdgcn_s_barrier();
    __builtin_amdgcn_sched_barrier(0);
}
__device__ __forceinline__ unsigned short bfb(float f) {
    __bf16 h = (__bf16)f;
    return __builtin_bit_cast(unsigned short, h);
}
__device__ __forceinline__ unsigned bpack(float a, float b) {
    return (unsigned)bfb(a) | ((unsigned)bfb(b) << 16);
}
__device__ __forceinline__ unsigned mpack(int x0, int x1) {
    unsigned m0 = (x0 != 0) ? 0x3F80u : 0u;   // bf16 1.0
    unsigned m1 = (x1 != 0) ? 0x3F80u : 0u;
    return m0 | (m1 << 16);
}

// 128-i tile, 512 threads (8 waves: wm 0..3 x wn 0..1), grid 256 = 1 block/CU.
// T3/T4/T5 port (m233 cure): each 64-o chunk split into 2 fine phases; per phase
// {6x ds_read_b128 frags || half-staging ds_writes || half global-load issue
//  -> s_barrier -> lgkmcnt(0) -> setprio(1) 10-MFMA cluster setprio(0) -> s_barrier}.
// vmcnt stays counted: staging consumes the OLDER register set while the newer
// set's loads remain in flight across barriers (2-deep prefetch, r12-verified).
__global__ __launch_bounds__(512, 1)
void gcn_fused(const float* __restrict__ nodes,
               const int* __restrict__ adj,
               const float* __restrict__ W,
               const float* __restrict__ Bm,
               float* __restrict__ out)
{
    __shared__ alignas(16) unsigned char lds[2 * BUF_STRIDE];

    // XCD swizzle: all 8 i-tiles of a batch on one XCD (nodes L2 locality)
    const int bid   = blockIdx.x;          // 256 = 32 batches x 8 itiles
    const int xcd   = bid & 7;
    const int slot  = bid >> 3;
    const int batch = ((slot >> 3) << 3) | xcd;
    const int itile = slot & 7;
    const int i0    = itile << 7;

    const int tid  = threadIdx.x;
    const int wave = tid >> 6;
    const int lane = tid & 63;
    const int wm   = wave >> 1;            // 0..3  (i 32-row slice)
    const int wn   = wave & 1;             // 0..1  (d 64-col slice)
    const int lrow = lane & 15;
    const int quad = lane >> 4;

    const int*   __restrict__ adj_b   = adj   + (size_t)batch * SEQ * SEQ;
    const float* __restrict__ nodes_b = nodes + (size_t)batch * SEQ * DIM;

    // staging thread mapping: 512 threads cover 64o x 128(i or d) per chunk
    const int a_row = (tid >> 5) * 4;      // o row group
    const int a_col = (tid & 31) * 4;      // i group (int4)
    const int n_col = (tid & 31) * 4;      // d group (float4)
    const int unit_s = (tid >> 5) >> 1;    // 16B unit of o-col in LDS row
    const int sub_s  = ((tid >> 5) & 1) * 8;

    f32x4v acc[2][4] = {};
    f32x4v acc_cnt[2] = {};
    bf16x8 ones;
    #pragma unroll
    for (int j = 0; j < 8; ++j) ones[j] = __builtin_bit_cast(__bf16, (unsigned short)0x3F80);

    // two named register staging sets (static indexing), 2-chunk prefetch
    i32x4  A0[4], A1[4];
    float4 N0[4], N1[4];

    auto load_adj = [&](int o0, i32x4 (&A)[4]) {
        const int* pa = adj_b + (size_t)(o0 + a_row) * SEQ + (i0 + a_col);
        #pragma unroll
        for (int r = 0; r < 4; ++r)
            A[r] = __builtin_nontemporal_load((const i32x4*)(pa + (size_t)r * SEQ));
    };
    auto load_nod = [&](int o0, float4 (&N)[4]) {
        const float* pn = nodes_b + (size_t)(o0 + a_row) * DIM + n_col;
        #pragma unroll
        for (int r = 0; r < 4; ++r) N[r] = *(const float4*)(pn + (size_t)r * DIM);
    };
    auto write_mask = [&](int base, const i32x4 (&A)[4]) {
        unsigned char* mb = lds + base;
        #pragma unroll
        for (int j = 0; j < 4; ++j) {
            uint2 w;
            w.x = mpack(A[0][j], A[1][j]);
            w.y = mpack(A[2][j], A[3][j]);
            *(uint2*)(mb + swz(a_col + j, unit_s) + sub_s) = w;
        }
    };
    auto write_nod = [&](int base, const float4 (&N)[4]) {
        unsigned char* nb = lds + base + NODES_OFF;
        #pragma unroll
        for (int j = 0; j < 4; ++j) {
            uint2 w;
            w.x = bpack(((const float*)&N[0])[j], ((const float*)&N[1])[j]);
            w.y = bpack(((const float*)&N[2])[j], ((const float*)&N[3])[j]);
            *(uint2*)(nb + swz(n_col + j, unit_s) + sub_s) = w;
        }
    };
    auto frags = [&](int base, int kk, bf16x8 (&av)[2], bf16x8 (&bv)[4]) {
        const unsigned char* mb = lds + base;
        const unsigned char* nb = lds + base + NODES_OFF;
        #pragma unroll
        for (int mf = 0; mf < 2; ++mf)
            av[mf] = *(const bf16x8*)(mb + swz(wm * 32 + mf * 16 + lrow, 4 * kk + quad));
        #pragma unroll
        for (int nf = 0; nf < 4; ++nf)
            bv[nf] = *(const bf16x8*)(nb + swz(wn * 64 + nf * 16 + lrow, 4 * kk + quad));
    };
    auto mfma_cluster = [&](const bf16x8 (&av)[2], const bf16x8 (&bv)[4]) {
        __builtin_amdgcn_s_setprio(1);
        #pragma unroll
        for (int mf = 0; mf < 2; ++mf) {
            #pragma unroll
            for (int nf = 0; nf < 4; ++nf)
                acc[mf][nf] = __builtin_amdgcn_mfma_f32_16x16x32_bf16(av[mf], bv[nf], acc[mf][nf], 0, 0, 0);
            acc_cnt[mf] = __builtin_amdgcn_mfma_f32_16x16x32_bf16(av[mf], ones, acc_cnt[mf], 0, 0, 0);
        }
        __builtin_amdgcn_s_setprio(0);
    };

    // prologue: R0<-c0, R1<-c1; stage c0; R0<-c2  (2-deep in flight)
    load_adj(0, A0);    load_nod(0, N0);
    load_adj(64, A1);   load_nod(64, N1);
    write_mask(0, A0);  write_nod(0, N0);
    load_adj(128, A0);  load_nod(128, N0);
    bar();

    for (int cc = 0; cc < 8; ++cc) {
        const int c0 = 2 * cc;
        bf16x8 av[2], bv[4];

        // P1: buf0/kk0  ||  stage mask(c+1)->buf1  ||  issue adj(c+3)
        frags(0, 0, av, bv);
        write_mask(BUF_STRIDE, A1);
        if (c0 + 3 < 16) load_adj((c0 + 3) * 64, A1);
        sbar(); lgkm0();
        mfma_cluster(av, bv);
        sbar();

        // P2: buf0/kk1  ||  stage nodes(c+1)->buf1  ||  issue nodes(c+3)
        frags(0, 1, av, bv);
        write_nod(BUF_STRIDE, N1);
        if (c0 + 3 < 16) load_nod((c0 + 3) * 64, N1);
        sbar(); lgkm0();
        mfma_cluster(av, bv);
        sbar();

        // P3: buf1/kk0  ||  stage mask(c+2)->buf0  ||  issue adj(c+4)
        frags(BUF_STRIDE, 0, av, bv);
        if (c0 + 2 < 16) write_mask(0, A0);
        if (c0 + 4 < 16) load_adj((c0 + 4) * 64, A0);
        sbar(); lgkm0();
        mfma_cluster(av, bv);
        sbar();

        // P4: buf1/kk1  ||  stage nodes(c+2)->buf0  ||  issue nodes(c+4)
        frags(BUF_STRIDE, 1, av, bv);
        if (c0 + 2 < 16) write_nod(0, N0);
        if (c0 + 4 < 16) load_nod((c0 + 4) * 64, N0);
        sbar(); lgkm0();
        mfma_cluster(av, bv);
        sbar();
    }

    // ---- epilogue (identical to r12): pooled 32K @0 + WT 32K @32K; then BT @0 ----
    #pragma unroll
    for (int mf = 0; mf < 2; ++mf) {
        #pragma unroll
        for (int r = 0; r < 4; ++r) {
            const int row = wm * 32 + mf * 16 + quad * 4 + r;
            const float cnt = acc_cnt[mf][r];
            const float inv = (cnt > 0.5f) ? 1.0f / cnt : 0.0f;
            #pragma unroll
            for (int nf = 0; nf < 4; ++nf) {
                const int col = wn * 64 + nf * 16 + lrow;
                *(unsigned short*)(lds + row * 256 + ((((col >> 3) ^ fxv(row >> 2)) << 4))
                                   + (col & 7) * 2) = bfb(acc[mf][nf][r] * inv);
            }
        }
    }

    const int n4 = (tid & 31) * 4;
    const int kg = tid >> 5;              // 0..15, covers k = kg*8..kg*8+7
    {
        float4 v[8];
        const float* pw = W + (size_t)(kg * 8) * DIM + n4;
        #pragma unroll
        for (int r = 0; r < 8; ++r) v[r] = *(const float4*)(pw + (size_t)r * DIM);
        #pragma unroll
        for (int j = 0; j < 4; ++j) {
            uint4 u;
            u.x = bpack(((const float*)&v[0])[j], ((const float*)&v[1])[j]);
            u.y = bpack(((const float*)&v[2])[j], ((const float*)&v[3])[j]);
            u.z = bpack(((const float*)&v[4])[j], ((const float*)&v[5])[j]);
            u.w = bpack(((const float*)&v[6])[j], ((const float*)&v[7])[j]);
            *(uint4*)(lds + BUF_STRIDE + swz256(n4 + j, kg)) = u;
        }
    }
    bar();

    f32x4v acc2[2][4] = {};

    // pooled @ W  (K=128): all operands from LDS b128 reads
    #pragma unroll
    for (int ks = 0; ks < 4; ++ks) {
        const int un = ks * 4 + quad;
        bf16x8 av[2], bv[4];
        #pragma unroll
        for (int mf = 0; mf < 2; ++mf)
            av[mf] = *(const bf16x8*)(lds + swz256(wm * 32 + mf * 16 + lrow, un));
        #pragma unroll
        for (int nf = 0; nf < 4; ++nf)
            bv[nf] = *(const bf16x8*)(lds + BUF_STRIDE + swz256(wn * 64 + nf * 16 + lrow, un));
        #pragma unroll
        for (int mf = 0; mf < 2; ++mf)
            #pragma unroll
            for (int nf = 0; nf < 4; ++nf)
                acc2[mf][nf] = __builtin_amdgcn_mfma_f32_16x16x32_bf16(av[mf], bv[nf], acc2[mf][nf], 0, 0, 0);
    }
    bar();   // all waves done reading pooled before BT overwrites it

    {
        float4 v[8];
        const float* pb = Bm + (size_t)(kg * 8) * DIM + n4;
        #pragma unroll
        for (int r = 0; r < 8; ++r) v[r] = *(const float4*)(pb + (size_t)r * DIM);
        #pragma unroll
        for (int j = 0; j < 4; ++j) {
            uint4 u;
            u.x = bpack(((const float*)&v[0])[j], ((const float*)&v[1])[j]);
            u.y = bpack(((const float*)&v[2])[j], ((const float*)&v[3])[j]);
            u.z = bpack(((const float*)&v[4])[j], ((const float*)&v[5])[j]);
            u.w = bpack(((const float*)&v[6])[j], ((const float*)&v[7])[j]);
            *(uint4*)(lds + swz256(n4 + j, kg)) = u;
        }
    }
    bar();

    // nodes @ B  (K=128): av from global f32 (L2-hot), bv from LDS
    #pragma unroll
    for (int ks = 0; ks < 4; ++ks) {
        const int k0 = ks * 32 + quad * 8;
        const int un = ks * 4 + quad;
        bf16x8 av[2], bv[4];
        #pragma unroll
        for (int mf = 0; mf < 2; ++mf) {
            const float* p = nodes_b + (size_t)(i0 + wm * 32 + mf * 16 + lrow) * DIM + k0;
            const float4 f1 = *(const float4*)p;
            const float4 f2 = *(const float4*)(p + 4);
            av[mf][0] = (__bf16)f1.x; av[mf][1] = (__bf16)f1.y;
            av[mf][2] = (__bf16)f1.z; av[mf][3] = (__bf16)f1.w;
            av[mf][4] = (__bf16)f2.x; av[mf][5] = (__bf16)f2.y;
            av[mf][6] = (__bf16)f2.z; av[mf][7] = (__bf16)f2.w;
        }
        #pragma unroll
        for (int nf = 0; nf < 4; ++nf)
            bv[nf] = *(const bf16x8*)(lds + swz256(wn * 64 + nf * 16 + lrow, un));
        #pragma unroll
        for (int mf = 0; mf < 2; ++mf)
            #pragma unroll
            for (int nf = 0; nf < 4; ++nf)
                acc2[mf][nf] = __builtin_amdgcn_mfma_f32_16x16x32_bf16(av[mf], bv[nf], acc2[mf][nf], 0, 0, 0);
    }

    // leaky-relu + PLAIN store (L2 write-combines the 4B scatter; r0: 16 MB exact)
    float* out_b = out + (size_t)batch * SEQ * DIM;
    #pragma unroll
    for (int mf = 0; mf < 2; ++mf) {
        #pragma unroll
        for (int nf = 0; nf < 4; ++nf) {
            const int col = wn * 64 + nf * 16 + lrow;
            #pragma unroll
            for (int r = 0; r < 4; ++r) {
                const int row = i0 + wm * 32 + mf * 16 + quad * 4 + r;
                const float x = acc2[mf][nf][r];
                out_b[(size_t)row * DIM + col] = (x > 0.0f) ? x : NEG_SLOPE * x;
            }
        }
    }
}

extern "C" void kernel_launch(void* const* d_in, const int* in_sizes, int n_in,
                              void* d_out, int out_size, void* d_ws, size_t ws_size,
                              hipStream_t stream) {
    const float* nodes = (const float*)d_in[0];
    const int*   adj   = (const int*)d_in[1];
    const float* W     = (const float*)d_in[2];
    const float* Bm    = (const float*)d_in[3];
    float*       out   = (float*)d_out;
    gcn_fused<<<dim3(256), dim3(512), 0, stream>>>(nodes, adj, W, Bm, out);
}